// Round 20
// baseline (376.896 us; speedup 1.0000x reference)
//
#include <hip/hip_runtime.h>
#include <cstdint>

#define NB 32
#define IC 2048
#define IK 16
#define OC 64
#define OD 32
#define ODF (OC*OD)          // 2048 flattened od
#define PARTBLK16 (16*ODF)   // slot: 16 local b (R16 format)
#define NCH0 128             // gemm0 ci chunks (16 i, 2 twins -> grid 256)
#define NCHF 256             // fused ci chunks (8 i, 2 twins -> grid 512)

typedef __fp16 h2 __attribute__((ext_vector_type(2)));
typedef __fp16 h8 __attribute__((ext_vector_type(8)));
typedef float  f4 __attribute__((ext_vector_type(4)));

__device__ __forceinline__ h2 pk2(float a, float b) {
#if __has_builtin(__builtin_amdgcn_cvt_pkrtz)
  return __builtin_amdgcn_cvt_pkrtz(a, b);
#else
  h2 r; r.x = (__fp16)a; r.y = (__fp16)b; return r;
#endif
}
__device__ __forceinline__ float fdot2a(h2 a, h2 b, float c) {
#if __has_builtin(__builtin_amdgcn_fdot2)
  return __builtin_amdgcn_fdot2(a, b, c, false);
#else
  return c + (float)a.x*(float)b.x + (float)a.y*(float)b.y;
#endif
}
__device__ __forceinline__ unsigned int bcu(h2 v){ return __builtin_bit_cast(unsigned int, v); }
__device__ __forceinline__ h2 bch2(unsigned int u){ return __builtin_bit_cast(h2, u); }
__device__ __forceinline__ h8 bch8(uint4 u){ return __builtin_bit_cast(h8, u); }
__device__ __forceinline__ f4 mfma_16x16x32(h8 a, h8 b, f4 c) {
  return __builtin_amdgcn_mfma_f32_16x16x32_f16(a, b, c, 0, 0, 0);
}
__device__ __forceinline__ uint4 packw(const float* wp) {
  const float4 wa = *(const float4*)wp;
  const float4 wb = *(const float4*)(wp + 4);
  uint4 au;
  au.x = bcu(pk2(wa.x, wa.y)); au.y = bcu(pk2(wa.z, wa.w));
  au.z = bcu(pk2(wb.x, wb.y)); au.w = bcu(pk2(wb.z, wb.w));
  return au;
}

// R17/R19 nulls: agree+saccum are at their SPLIT-structure floor (~95us/iter,
// 2x Whg streams + 32MB cg round-trip). Softmax is over o only -> the whole
// iteration is i-local -> FUSE with the dense R16 math: per i-pair,
// P1 sum/diff agreements | BAR | per-row softmax (LDS c_s) | BAR |
// P3 re-read pair's Whg window (L2-hot) with c folded into x, acc in regs.
// LDS ~26KB -> 2 wg/CU = 32 waves (max). 9 barriers/wg.

// K0: iter-1 GEMM (c=1/64 exact), two i per MFMA, bh twins (R16-verified).
template<int WH>
__global__ __launch_bounds__(1024)
void caps_gemm0(const float* __restrict__ xg, const float* __restrict__ Wg,
                uint4* __restrict__ Whg, float* __restrict__ part)
{
  __shared__ uint4 x_h[8][2][16];
  const int t = threadIdx.x, w = t >> 6, l = t & 63, lb = l & 15, lg = l >> 4;
  const int bid = blockIdx.x, slot = bid >> 3;
  const int bh = slot & 1;
  const int ci = (bid & 7)*16 + (slot >> 1);     // XCD-grouped twins
  const int i0 = ci*16, bg0 = bh*16;
  const f4 zf = {0.f,0.f,0.f,0.f};
  f4 acc[8];
#pragma unroll
  for (int q = 0; q < 8; ++q) acc[q] = zf;

  for (int g8 = 0; g8 < 16; g8 += 8) {
    if (g8) __syncthreads();
    if (t < 256) {
      const int si = t >> 5, kc2 = (t >> 4) & 1, sb = t & 15;
      const float* xp = &xg[((size_t)(bg0 + sb)*IC + (i0 + g8 + si))*IK + kc2*8];
      x_h[si][kc2][sb] = packw(xp);
    }
    __syncthreads();
#pragma unroll 1
    for (int p = 0; p < 4; ++p) {
      const int isel = lg >> 1, kc = lg & 1, il = p*2 + isel;
      const h8 B = bch8(x_h[il][kc][lb]);
#pragma unroll
      for (int tt = 0; tt < 8; ++tt) {
        const size_t widx = (size_t)(i0 + g8 + il)*ODF + (w*8 + tt)*16 + lb;
        const uint4 au = packw(&Wg[widx*IK + kc*8]);
        if (WH && bh == 0) Whg[widx*2 + kc] = au;
        acc[tt] = mfma_16x16x32(bch8(au), B, acc[tt]);
      }
    }
  }
  float* pp = part + (size_t)(ci*2 + bh)*PARTBLK16;
#pragma unroll
  for (int tt = 0; tt < 8; ++tt) {
    float4 st;
    st.x = acc[tt].x*(1.f/64.f); st.y = acc[tt].y*(1.f/64.f);
    st.z = acc[tt].z*(1.f/64.f); st.w = acc[tt].w*(1.f/64.f);
    *(float4*)&pp[(size_t)lb*ODF + (w*8 + tt)*16 + lg*4] = st;
  }
}

// Fused agreement+softmax+saccum, one kernel per routing iteration.
// grid 512 (8-i chunks x 2 bh twins, XCD-grouped). R16's verified dense
// sum/diff math for agreements; c folded into x for the s-accumulate.
template<int ITER, int WH>
__global__ __launch_bounds__(1024)
void caps_fused(const float* __restrict__ xg, const float* __restrict__ Wg,
                const uint4* __restrict__ Whg, const float* __restrict__ vin,
                float* __restrict__ a1g, float* __restrict__ part)
{
  __shared__ uint4 x_h[8][2][16];                // 8 KB
  __shared__ float agr[2*64*17];                 // 8.7 KB [pi][o][b]
  __shared__ float c_s[2*16*69];                 // 8.8 KB [pi][b][o69]
  const int t = threadIdx.x, w = t >> 6, l = t & 63, lb = l & 15, lg = l >> 4;
  const int bid = blockIdx.x, slot = bid >> 3;
  const int bh = slot & 1;
  const int ci8 = (bid & 7)*32 + (slot >> 1);    // 0..255
  const int i0 = ci8*8, bg0 = bh*16;
  const f4 zf = {0.f,0.f,0.f,0.f};
  const int isel = lg >> 1, kc = lg & 1;
  const unsigned int msk = (lg >= 2) ? 0x80008000u : 0u;

  f4 acc[8];
#pragma unroll
  for (int q = 0; q < 8; ++q) acc[q] = zf;

  if (t < 256) {
    const int si = t >> 5, kc2 = (t >> 4) & 1, sb = t & 15;
    const float* xp = &xg[((size_t)(bg0 + sb)*IC + (i0 + si))*IK + kc2*8];
    x_h[si][kc2][sb] = packw(xp);
  }
  __syncthreads();

#pragma unroll 1
  for (int p = 0; p < 4; ++p) {
    const int iA = i0 + p*2, iB = iA + 1;
    const uint4 bu = x_h[p*2 + isel][kc][lb];
    uint4 bm;
    bm.x = bu.x^msk; bm.y = bu.y^msk; bm.z = bu.z^msk; bm.w = bu.w^msk;
    const h8 Bp = bch8(bu), Bm = bch8(bm);
    // ---- P1: agreements via sum/diff MFMAs (v loaded per-tt, L2-hot) ----
    float ap1[4] = {0.f,0.f,0.f,0.f}, ap2[4] = {0.f,0.f,0.f,0.f};
#pragma unroll
    for (int tt = 0; tt < 8; ++tt) {
      const size_t widx = (size_t)(iA + isel)*ODF + (w*8 + tt)*16 + lb;
      const uint4 au = WH ? Whg[widx*2 + kc] : packw(&Wg[widx*IK + kc*8]);
      const h8 A = bch8(au);
      const f4 s = mfma_16x16x32(A, Bp, zf);     // u_iA + u_iB
      const f4 d = mfma_16x16x32(A, Bm, zf);     // u_iA - u_iB
      const int o = w*4 + (tt >> 1);
      const float4 vv = *(const float4*)
        &vin[((size_t)(bg0 + lb)*OC + o)*OD + (tt & 1)*16 + lg*4];
      const h2 vh0 = pk2(vv.x, vv.y), vh1 = pk2(vv.z, vv.w);
      const h2 sh0 = pk2(s.x, s.y), sh1 = pk2(s.z, s.w);
      const h2 dh0 = pk2(d.x, d.y), dh1 = pk2(d.z, d.w);
      const float ds = fdot2a(sh0, vh0, fdot2a(sh1, vh1, 0.f));
      const float dd = fdot2a(dh0, vh0, fdot2a(dh1, vh1, 0.f));
      ap1[tt >> 1] += ds + dd;                   // 2*(u_iA . v)
      ap2[tt >> 1] += ds - dd;                   // 2*(u_iB . v)
    }
#pragma unroll
    for (int q = 0; q < 4; ++q) {
      float a1v = ap1[q], a2v = ap2[q];
      a1v += __shfl_xor(a1v, 16); a1v += __shfl_xor(a1v, 32);
      a2v += __shfl_xor(a2v, 16); a2v += __shfl_xor(a2v, 32);
      if (l < 16) {
        const int o = w*4 + q;
        float b1 = 0.5f*a1v, b2 = 0.5f*a2v;
        if (ITER == 2) {
          b1 += a1g[((size_t)iA*OC + o)*NB + bg0 + lb];
          b2 += a1g[((size_t)iB*OC + o)*NB + bg0 + lb];
        }
        if (ITER == 1) {
          a1g[((size_t)iA*OC + o)*NB + bg0 + lb] = b1;
          a1g[((size_t)iB*OC + o)*NB + bg0 + lb] = b2;
        }
        agr[(0*64 + o)*17 + lb] = b1;
        agr[(1*64 + o)*17 + lb] = b2;
      }
    }
    __syncthreads();
    // ---- softmax: 32 rows (pi,b) over o; wave w handles b=w, both pi ----
#pragma unroll
    for (int r = 0; r < 2; ++r) {
      const float a = agr[(r*64 + l)*17 + w];    // o = l
      float m = a;
#pragma unroll
      for (int off = 1; off < 64; off <<= 1) m = fmaxf(m, __shfl_xor(m, off));
      const float e = __expf(a - m);
      float se = e;
#pragma unroll
      for (int off = 1; off < 64; off <<= 1) se += __shfl_xor(se, off);
      c_s[(r*16 + w)*69 + l] = e / se;
    }
    __syncthreads();
    // ---- P3: re-read pair's Whg window (L2-hot), c folded into x ----
#pragma unroll
    for (int tt = 0; tt < 8; ++tt) {
      const int o = w*4 + (tt >> 1);
      const float cs = c_s[(isel*16 + lb)*69 + o];   // my K-half's i
      const h2 cpk = pk2(cs, cs);
      uint4 bs;
      bs.x = bcu(bch2(bu.x)*cpk); bs.y = bcu(bch2(bu.y)*cpk);
      bs.z = bcu(bch2(bu.z)*cpk); bs.w = bcu(bch2(bu.w)*cpk);
      const size_t widx = (size_t)(iA + isel)*ODF + (w*8 + tt)*16 + lb;
      const uint4 au = WH ? Whg[widx*2 + kc] : packw(&Wg[widx*IK + kc*8]);
      acc[tt] = mfma_16x16x32(bch8(au), bch8(bs), acc[tt]);  // += c1*uA+c2*uB
    }
    // no barrier: next P1 touches agr only; c_s hazard is covered by the
    // P1->softmax barrier of the next pair.
  }
  float* pp = part + (size_t)(ci8*2 + bh)*PARTBLK16;
#pragma unroll
  for (int tt = 0; tt < 8; ++tt) {
    const f4 a = acc[tt];
    float4 st; st.x = a.x; st.y = a.y; st.z = a.z; st.w = a.w;
    *(float4*)&pp[(size_t)lb*ODF + (w*8 + tt)*16 + lg*4] = st;
  }
}

// Sum nci*2 slots (16-b format, bh twins) and apply squash.
__global__ __launch_bounds__(64)
void caps_reduce(const float* __restrict__ part, int nci, float* __restrict__ vout)
{
  const int r  = blockIdx.x;           // b*OC + o
  const int b  = r >> 6, o = r & 63;
  const int bh = b >> 4, bl = b & 15;
  const int d  = threadIdx.x & 31;
  const int h  = threadIdx.x >> 5;
  const int half = nci >> 1;
  const float* p = part + (size_t)bh*PARTBLK16 + (size_t)bl*ODF + o*OD + d;
  float s = 0.f;
#pragma unroll 4
  for (int q = 0; q < half; ++q)
    s += p[(size_t)((h*half + q)*2)*PARTBLK16];
  s += __shfl_xor(s, 32);
  float n2 = s*s;
#pragma unroll
  for (int off = 1; off < 32; off <<= 1) n2 += __shfl_xor(n2, off);
  const float n = sqrtf(n2);
  const float f = n2 / ((1.f + n2)*(n + 1e-8f));
  if (h == 0) vout[(size_t)r*OD + d] = s*f;
}

extern "C" void kernel_launch(void* const* d_in, const int* in_sizes, int n_in,
                              void* d_out, int out_size, void* d_ws, size_t ws_size,
                              hipStream_t stream)
{
  const float* xg = (const float*)d_in[0];
  const float* Wg = (const float*)d_in[1];
  float* out = (float*)d_out;

  const size_t part_b = (size_t)NCHF*2*PARTBLK16*sizeof(float); // 64 MB
  const size_t a1_b   = (size_t)IC*OC*NB*sizeof(float);         // 16 MB
  const size_t v_b    = (size_t)NB*ODF*sizeof(float);           // 256 KB
  const size_t wh_b   = (size_t)IC*ODF*IK*2;                    // 128 MB f16 W

  char* ws = (char*)d_ws;
  float* part = (float*)ws;                  ws += part_b;
  float* a1g  = (float*)ws;                  ws += a1_b;
  float* vbuf = (float*)ws;                  ws += v_b;
  uint4* whg  = (uint4*)ws;
  const bool WH = (part_b + a1_b + v_b + wh_b) <= ws_size;

  if (WH) {
    caps_gemm0<1><<<NCH0*2, 1024, 0, stream>>>(xg, Wg, whg, part);
    caps_reduce<<<NB*OC, 64, 0, stream>>>(part, NCH0, vbuf);
    caps_fused<1,1><<<NCHF*2, 1024, 0, stream>>>(xg, Wg, whg, vbuf, a1g, part);
    caps_reduce<<<NB*OC, 64, 0, stream>>>(part, NCHF, vbuf);
    caps_fused<2,1><<<NCHF*2, 1024, 0, stream>>>(xg, Wg, whg, vbuf, a1g, part);
    caps_reduce<<<NB*OC, 64, 0, stream>>>(part, NCHF, out);
  } else {
    caps_gemm0<0><<<NCH0*2, 1024, 0, stream>>>(xg, Wg, nullptr, part);
    caps_reduce<<<NB*OC, 64, 0, stream>>>(part, NCH0, vbuf);
    caps_fused<1,0><<<NCHF*2, 1024, 0, stream>>>(xg, Wg, nullptr, vbuf, a1g, part);
    caps_reduce<<<NB*OC, 64, 0, stream>>>(part, NCHF, vbuf);
    caps_fused<2,0><<<NCHF*2, 1024, 0, stream>>>(xg, Wg, nullptr, vbuf, a1g, part);
    caps_reduce<<<NB*OC, 64, 0, stream>>>(part, NCHF, out);
  }
}

// Round 21
// 287.817 us; speedup vs baseline: 1.3095x; 1.3095x over previous
//
#include <hip/hip_runtime.h>
#include <cstdint>

#define NB 32
#define IC 2048
#define IK 16
#define OC 64
#define OD 32
#define ODF (OC*OD)          // 2048 flattened od
#define PARTBLK (16*ODF)     // 32768 floats per slot (16 local b)
#define NCH 128              // 16-i chunks for gemm0/saccum (grid 256)
#define NSLOT (NCH*2)

typedef __fp16 h2 __attribute__((ext_vector_type(2)));
typedef __fp16 h8 __attribute__((ext_vector_type(8)));
typedef float  f4 __attribute__((ext_vector_type(4)));

__device__ __forceinline__ h2 pk2(float a, float b) {
#if __has_builtin(__builtin_amdgcn_cvt_pkrtz)
  return __builtin_amdgcn_cvt_pkrtz(a, b);
#else
  h2 r; r.x = (__fp16)a; r.y = (__fp16)b; return r;
#endif
}
__device__ __forceinline__ float fdot2a(h2 a, h2 b, float c) {
#if __has_builtin(__builtin_amdgcn_fdot2)
  return __builtin_amdgcn_fdot2(a, b, c, false);
#else
  return c + (float)a.x*(float)b.x + (float)a.y*(float)b.y;
#endif
}
__device__ __forceinline__ unsigned int bcu(h2 v){ return __builtin_bit_cast(unsigned int, v); }
__device__ __forceinline__ h2 bch2(unsigned int u){ return __builtin_bit_cast(h2, u); }
__device__ __forceinline__ h8 bch8(uint4 u){ return __builtin_bit_cast(h8, u); }
__device__ __forceinline__ f4 mfma_16x16x32(h8 a, h8 b, f4 c) {
  return __builtin_amdgcn_mfma_f32_16x16x32_f16(a, b, c, 0, 0, 0);
}
__device__ __forceinline__ uint4 packw(const float* wp) {
  const float4 wa = *(const float4*)wp;
  const float4 wb = *(const float4*)(wp + 4);
  uint4 au;
  au.x = bcu(pk2(wa.x, wa.y)); au.y = bcu(pk2(wa.z, wa.w));
  au.z = bcu(pk2(wb.x, wb.y)); au.w = bcu(pk2(wb.z, wb.w));
  return au;
}

// FINAL (R16 structure, best measured: 286.7us, absmax 3.9e-3).
// Ladder: 1162 (R3 spill) -> 665 (LDS s-tile) -> 362 (MFMA) -> 287 (dense
// lanes + decoupled streaming kernels). R17-R20 structural variants
// (wg-count, all-32-b, Whg-once, fusion) all regressed or null ->
// gemm0 at stream roofline (5.7 TB/s), iteration kernels at effective
// HBM+L3 ceiling (twin Whg re-reads are L3-hits; R19 proved it).

// K0: iter-1 GEMM (c=1/64 exact), two i per MFMA (K=32). WH: also emits
// the packed-f16 W copy (bh==0 twins) that later passes stream at half BW.
template<int WH>
__global__ __launch_bounds__(1024)
void caps_gemm0(const float* __restrict__ xg, const float* __restrict__ Wg,
                uint4* __restrict__ Whg, float* __restrict__ part)
{
  __shared__ uint4 x_h[8][2][16];
  const int t = threadIdx.x, w = t >> 6, l = t & 63, lb = l & 15, lg = l >> 4;
  const int bid = blockIdx.x, slot = bid >> 3;
  const int bh = slot & 1;
  const int ci = (bid & 7)*16 + (slot >> 1);     // XCD-grouped twins
  const int i0 = ci*16, bg0 = bh*16;
  const f4 zf = {0.f,0.f,0.f,0.f};
  f4 acc[8];
#pragma unroll
  for (int q = 0; q < 8; ++q) acc[q] = zf;

  for (int g8 = 0; g8 < 16; g8 += 8) {
    if (g8) __syncthreads();
    if (t < 256) {
      const int si = t >> 5, kc2 = (t >> 4) & 1, sb = t & 15;
      const float* xp = &xg[((size_t)(bg0 + sb)*IC + (i0 + g8 + si))*IK + kc2*8];
      x_h[si][kc2][sb] = packw(xp);
    }
    __syncthreads();
#pragma unroll 1
    for (int p = 0; p < 4; ++p) {
      const int isel = lg >> 1, kc = lg & 1, il = p*2 + isel;
      const h8 B = bch8(x_h[il][kc][lb]);
#pragma unroll
      for (int tt = 0; tt < 8; ++tt) {
        const size_t widx = (size_t)(i0 + g8 + il)*ODF + (w*8 + tt)*16 + lb;
        const uint4 au = packw(&Wg[widx*IK + kc*8]);
        if (WH && bh == 0) Whg[widx*2 + kc] = au;
        acc[tt] = mfma_16x16x32(bch8(au), B, acc[tt]);
      }
    }
  }
  float* pp = part + (size_t)(ci*2 + bh)*PARTBLK;
#pragma unroll
  for (int tt = 0; tt < 8; ++tt) {
    float4 st;
    st.x = acc[tt].x*(1.f/64.f); st.y = acc[tt].y*(1.f/64.f);
    st.z = acc[tt].z*(1.f/64.f); st.w = acc[tt].w*(1.f/64.f);
    *(float4*)&pp[(size_t)lb*ODF + (w*8 + tt)*16 + lg*4] = st;
  }
}

// KA: agreement + softmax + coalesced c write, sum/diff dense form.
// grid 512 (8-i chunks x 2 bh), 3 barriers. v held as packed f16 * 0.5.
template<int ITER, int WH>
__global__ __launch_bounds__(1024)
void caps_agree(const float* __restrict__ xg, const float* __restrict__ Wg,
                const uint4* __restrict__ Whg, const float* __restrict__ vin,
                float* __restrict__ a1g, float* __restrict__ cg)
{
  __shared__ uint4 x_h[8][2][16];
  __shared__ float agr[8*64*17];                 // 34.8 KB [ii][o][b]
  const int t = threadIdx.x, w = t >> 6, l = t & 63, lb = l & 15, lg = l >> 4;
  const int bid = blockIdx.x, slot = bid >> 3;
  const int bh = slot & 1;
  const int ci8 = (bid & 7)*32 + (slot >> 1);    // 0..255
  const int i0 = ci8*8, bg0 = bh*16;
  const f4 zf = {0.f,0.f,0.f,0.f};

  if (t < 256) {
    const int si = t >> 5, kc2 = (t >> 4) & 1, sb = t & 15;
    const float* xp = &xg[((size_t)(bg0 + sb)*IC + (i0 + si))*IK + kc2*8];
    x_h[si][kc2][sb] = packw(xp);
  }
  unsigned int vh[16];                           // v*0.5 f16, i-invariant
#pragma unroll
  for (int tt = 0; tt < 8; ++tt) {
    const int o = w*4 + (tt >> 1);
    const float4 vv = *(const float4*)
      &vin[((size_t)(bg0 + lb)*OC + o)*OD + (tt & 1)*16 + lg*4];
    vh[tt*2]   = bcu(pk2(0.5f*vv.x, 0.5f*vv.y));
    vh[tt*2+1] = bcu(pk2(0.5f*vv.z, 0.5f*vv.w));
  }
  __syncthreads();

  const int isel = lg >> 1, kc = lg & 1;
  const unsigned int msk = (lg >= 2) ? 0x80008000u : 0u;   // negate i2 K-half

#pragma unroll 2
  for (int p = 0; p < 4; ++p) {                  // i-pair
    const int iA = i0 + p*2, iB = iA + 1;
    const uint4 bu = x_h[p*2 + isel][kc][lb];
    uint4 bm;
    bm.x = bu.x^msk; bm.y = bu.y^msk; bm.z = bu.z^msk; bm.w = bu.w^msk;
    const h8 Bp = bch8(bu), Bm = bch8(bm);
    float ap1[4] = {0.f,0.f,0.f,0.f}, ap2[4] = {0.f,0.f,0.f,0.f};
#pragma unroll
    for (int tt = 0; tt < 8; ++tt) {
      const size_t widx = (size_t)(iA + isel)*ODF + (w*8 + tt)*16 + lb;
      const uint4 au = WH ? Whg[widx*2 + kc] : packw(&Wg[widx*IK + kc*8]);
      const h8 A = bch8(au);
      const f4 s = mfma_16x16x32(A, Bp, zf);     // u_iA + u_iB
      const f4 d = mfma_16x16x32(A, Bm, zf);     // u_iA - u_iB
      const h2 sh0 = pk2(s.x, s.y), sh1 = pk2(s.z, s.w);
      const h2 dh0 = pk2(d.x, d.y), dh1 = pk2(d.z, d.w);
      const float ds = fdot2a(sh0, bch2(vh[tt*2]), fdot2a(sh1, bch2(vh[tt*2+1]), 0.f));
      const float dd = fdot2a(dh0, bch2(vh[tt*2]), fdot2a(dh1, bch2(vh[tt*2+1]), 0.f));
      ap1[tt >> 1] += ds + dd;                   // u_iA . v
      ap2[tt >> 1] += ds - dd;                   // u_iB . v
    }
#pragma unroll
    for (int q = 0; q < 4; ++q) {
      float a1v = ap1[q], a2v = ap2[q];
      a1v += __shfl_xor(a1v, 16); a1v += __shfl_xor(a1v, 32);
      a2v += __shfl_xor(a2v, 16); a2v += __shfl_xor(a2v, 32);
      if (l < 16) {
        const int o = w*4 + q;
        float b1 = a1v, b2 = a2v;
        if (ITER == 2) {
          b1 += a1g[((size_t)iA*OC + o)*NB + bg0 + lb];
          b2 += a1g[((size_t)iB*OC + o)*NB + bg0 + lb];
        }
        if (ITER == 1) {
          a1g[((size_t)iA*OC + o)*NB + bg0 + lb] = b1;
          a1g[((size_t)iB*OC + o)*NB + bg0 + lb] = b2;
        }
        agr[((p*2)*64 + o)*17 + lb]   = b1;
        agr[((p*2+1)*64 + o)*17 + lb] = b2;
      }
    }
  }
  __syncthreads();
  // batched softmax: 128 (i,b) rows, 8 per wave; c overwrites agr in place
#pragma unroll
  for (int r = 0; r < 8; ++r) {
    const int row = w*8 + r, si = row >> 4, b = row & 15;
    const float a = agr[(si*64 + l)*17 + b];     // o = l
    float m = a;
#pragma unroll
    for (int off = 1; off < 64; off <<= 1) m = fmaxf(m, __shfl_xor(m, off));
    const float e = __expf(a - m);
    float se = e;
#pragma unroll
    for (int off = 1; off < 64; off <<= 1) se += __shfl_xor(se, off);
    agr[(si*64 + l)*17 + b] = e / se;
  }
  __syncthreads();
  // coalesced c flush: [i][o][b], 64B segments
#pragma unroll
  for (int cc = 0; cc < 8; ++cc) {
    const int o = t >> 4, b2 = t & 15;
    cg[((size_t)(i0 + cc)*OC + o)*NB + bg0 + b2] = agr[(cc*64 + o)*17 + b2];
  }
}

// KB: s accumulation — c folded into the B fragment (pk f16 mul), direct
// MFMA accumulate over i-pairs (K=32 dense). grid 256, acc in regs.
template<int WH>
__global__ __launch_bounds__(1024)
void caps_saccum(const float* __restrict__ xg, const float* __restrict__ Wg,
                 const uint4* __restrict__ Whg, const float* __restrict__ cg,
                 float* __restrict__ part)
{
  __shared__ uint4 x_h[8][2][16];
  const int t = threadIdx.x, w = t >> 6, l = t & 63, lb = l & 15, lg = l >> 4;
  const int bid = blockIdx.x, slot = bid >> 3;
  const int bh = slot & 1;
  const int ci = (bid & 7)*16 + (slot >> 1);
  const int i0 = ci*16, bg0 = bh*16;
  const f4 zf = {0.f,0.f,0.f,0.f};
  f4 acc[8];
#pragma unroll
  for (int q = 0; q < 8; ++q) acc[q] = zf;
  const int isel = lg >> 1, kc = lg & 1;

  for (int g8 = 0; g8 < 16; g8 += 8) {
    if (g8) __syncthreads();
    if (t < 256) {
      const int si = t >> 5, kc2 = (t >> 4) & 1, sb = t & 15;
      const float* xp = &xg[((size_t)(bg0 + sb)*IC + (i0 + g8 + si))*IK + kc2*8];
      x_h[si][kc2][sb] = packw(xp);
    }
    __syncthreads();
#pragma unroll 1
    for (int p = 0; p < 4; ++p) {
      const int iA = i0 + g8 + p*2, iB = iA + 1;
      const uint4 bu = x_h[p*2 + isel][kc][lb];
#pragma unroll
      for (int q = 0; q < 4; ++q) {              // o-quad; 2 tiles share o
        const int o = w*4 + q;
        const float c1 = cg[((size_t)iA*OC + o)*NB + bg0 + lb];
        const float c2 = cg[((size_t)iB*OC + o)*NB + bg0 + lb];
        const float cs = (lg < 2) ? c1 : c2;     // my K-half's i
        const h2 cpk = pk2(cs, cs);
        uint4 bs;
        bs.x = bcu(bch2(bu.x)*cpk); bs.y = bcu(bch2(bu.y)*cpk);
        bs.z = bcu(bch2(bu.z)*cpk); bs.w = bcu(bch2(bu.w)*cpk);
        const h8 Bs = bch8(bs);
#pragma unroll
        for (int th = 0; th < 2; ++th) {
          const int tt = q*2 + th;
          const size_t widx = (size_t)(iA + isel)*ODF + (w*8 + tt)*16 + lb;
          const uint4 au = WH ? Whg[widx*2 + kc] : packw(&Wg[widx*IK + kc*8]);
          acc[tt] = mfma_16x16x32(bch8(au), Bs, acc[tt]);   // += c1*uA + c2*uB
        }
      }
    }
  }
  float* pp = part + (size_t)(ci*2 + bh)*PARTBLK;
#pragma unroll
  for (int tt = 0; tt < 8; ++tt) {
    float4 st; st.x = acc[tt].x; st.y = acc[tt].y; st.z = acc[tt].z; st.w = acc[tt].w;
    *(float4*)&pp[(size_t)lb*ODF + (w*8 + tt)*16 + lg*4] = st;
  }
}

// Sum the 256 slots and apply squash.
__global__ __launch_bounds__(64)
void caps_reduce(const float* __restrict__ part, float* __restrict__ vout)
{
  const int r  = blockIdx.x;           // b*OC + o
  const int b  = r >> 6, o = r & 63;
  const int bh = b >> 4, bl = b & 15;
  const int d  = threadIdx.x & 31;
  const int h  = threadIdx.x >> 5;
  const float* p = part + (size_t)bh*PARTBLK + (size_t)bl*ODF + o*OD + d;
  float s = 0.f;
#pragma unroll 4
  for (int q = 0; q < NCH/2; ++q)
    s += p[(size_t)((h*(NCH/2) + q)*2)*PARTBLK];
  s += __shfl_xor(s, 32);
  float n2 = s*s;
#pragma unroll
  for (int off = 1; off < 32; off <<= 1) n2 += __shfl_xor(n2, off);
  const float n = sqrtf(n2);
  const float f = n2 / ((1.f + n2)*(n + 1e-8f));
  if (h == 0) vout[(size_t)r*OD + d] = s*f;
}

extern "C" void kernel_launch(void* const* d_in, const int* in_sizes, int n_in,
                              void* d_out, int out_size, void* d_ws, size_t ws_size,
                              hipStream_t stream)
{
  const float* xg = (const float*)d_in[0];
  const float* Wg = (const float*)d_in[1];
  float* out = (float*)d_out;

  const size_t part_b = (size_t)NSLOT*PARTBLK*sizeof(float);   // 32 MB
  const size_t a1_b   = (size_t)IC*OC*NB*sizeof(float);        // 16 MB
  const size_t c_b    = a1_b;                                  // 16 MB
  const size_t v_b    = (size_t)NB*ODF*sizeof(float);          // 256 KB
  const size_t wh_b   = (size_t)IC*ODF*IK*2;                   // 128 MB f16 W

  char* ws = (char*)d_ws;
  float* part = (float*)ws;                  ws += part_b;
  float* a1g  = (float*)ws;                  ws += a1_b;
  float* cg   = (float*)ws;                  ws += c_b;
  float* vbuf = (float*)ws;                  ws += v_b;
  uint4* whg  = (uint4*)ws;
  const bool WH = (part_b + a1_b + c_b + v_b + wh_b) <= ws_size;

  if (WH) {
    caps_gemm0<1><<<NSLOT, 1024, 0, stream>>>(xg, Wg, whg, part);
    caps_reduce<<<NB*OC, 64, 0, stream>>>(part, vbuf);
    caps_agree<1,1><<<512, 1024, 0, stream>>>(xg, Wg, whg, vbuf, a1g, cg);
    caps_saccum<1><<<NSLOT, 1024, 0, stream>>>(xg, Wg, whg, cg, part);
    caps_reduce<<<NB*OC, 64, 0, stream>>>(part, vbuf);
    caps_agree<2,1><<<512, 1024, 0, stream>>>(xg, Wg, whg, vbuf, a1g, cg);
    caps_saccum<1><<<NSLOT, 1024, 0, stream>>>(xg, Wg, whg, cg, part);
    caps_reduce<<<NB*OC, 64, 0, stream>>>(part, out);
  } else {
    caps_gemm0<0><<<NSLOT, 1024, 0, stream>>>(xg, Wg, nullptr, part);
    caps_reduce<<<NB*OC, 64, 0, stream>>>(part, vbuf);
    caps_agree<1,0><<<512, 1024, 0, stream>>>(xg, Wg, nullptr, vbuf, a1g, cg);
    caps_saccum<0><<<NSLOT, 1024, 0, stream>>>(xg, Wg, nullptr, cg, part);
    caps_reduce<<<NB*OC, 64, 0, stream>>>(part, vbuf);
    caps_agree<2,0><<<512, 1024, 0, stream>>>(xg, Wg, nullptr, vbuf, a1g, cg);
    caps_saccum<0><<<NSLOT, 1024, 0, stream>>>(xg, Wg, nullptr, cg, part);
    caps_reduce<<<NB*OC, 64, 0, stream>>>(part, out);
  }
}